// Round 3
// baseline (4287.814 us; speedup 1.0000x reference)
//
#include <hip/hip_runtime.h>

// ============================================================================
// V3: LDS-resident x tile. One block = 64 nodes; stages x[64][208] -> LDS
// [208][65] (conflict-free) once, directly from x (transpose kernel deleted).
// 4 waves split output channels (8/8/4 of 0e/1o/2e); lane = node.
// All x re-reads hit LDS; weights stream as uniform float4 (L2-hot).
// x HBM traffic: exactly once (166 MB). Line-aligned output writes.
//
// ws float layout:
//   [0,363)    w3j tables (read directly from global in main kernel)
//   [512,...)  merged/symmetrized weights (V1 layouts, see OFF_*)
// ============================================================================
#define T000 0
#define T011 1
#define T101 10
#define T110 19
#define T022 28
#define T202 53
#define T220 78
#define T121 103
#define T211 148
#define T112 193
#define T222 238
#define NTAB 363

// source tp_w offsets (verified: total 208896)
#define TP000 0
#define TP011 32768
#define TP022 65536
#define TP101 73728
#define TP110 106496
#define TP112 139264
#define TP121 155648
#define TP202 172032
#define TP211 180224
#define TP220 196608
#define TP222 204800

// destination (prepared) weight offsets (V1 baseline layouts)
#define OFF_CW000 512      // [pid528][w32]
#define OFF_CW110 17408    // [pid528][w32]
#define OFF_CW220 34304    // [pid136][w32]
#define OFF_CW011 38656    // [q32][p32][w32]  merged 011+101
#define OFF_CW121 71424    // [b16][q32][w32]  merged 121+211
#define OFF_CW022 87808    // [b16][p32][w16]  merged 022+202
#define OFF_CW112 96000    // [pid528][w16]
#define OFF_CW222 104448   // [pid136][w16]
#define OFF_LIN0  106624   // [32][32]
#define OFF_LIN1  107648   // [32][32]
#define OFF_LIN2  108672   // [16][16]
#define PREP_THREADS 108416

// ============================================================================
// Parallel device-side Wigner 3j (literal reference math, fp64, 1 thr/element)
// ============================================================================
struct cplx { double re, im; };
__device__ inline cplx cmul(cplx a, cplx b){ return {a.re*b.re - a.im*b.im, a.re*b.im + a.im*b.re}; }

__device__ double dfact(int n){ double r=1; for(int i=2;i<=n;i++) r*=i; return r; }

__device__ double dcgc(int j1,int m1,int j2,int m2,int j3,int m3){
  if (m3 != m1+m2) return 0.0;
  double pref = sqrt((2.0*j3+1)*dfact(j3+j1-j2)*dfact(j3-j1+j2)*dfact(j1+j2-j3)/dfact(j1+j2+j3+1));
  pref *= sqrt(dfact(j3+m3)*dfact(j3-m3)*dfact(j1-m1)*dfact(j1+m1)*dfact(j2-m2)*dfact(j2+m2));
  int k0 = max(0, max(j2-j3-m1, j1-j3+m2));
  int k1 = min(j1+j2-j3, min(j1-m1, j2+m2));
  double s = 0.0;
  for(int k=k0;k<=k1;k++){
    double d = dfact(k)*dfact(j1+j2-j3-k)*dfact(j1-m1-k)*dfact(j2+m2-k)*dfact(j3-j2+m1+k)*dfact(j3-j1-m2+k);
    s += ((k&1)?-1.0:1.0)/d;
  }
  return pref*s;
}

__device__ cplx qel(int l, int a, int c){
  const double s2 = 0.7071067811865475244;
  cplx base = {0.0, 0.0};
  if (a < l){
    if (c == 2*l-a) base = {s2, 0.0};
    else if (c == a) base = {0.0, -s2};
  } else if (a == l){
    if (c == l) base = {1.0, 0.0};
  } else {
    double sgn = ((a-l)&1)? -1.0 : 1.0;
    if (c == a) base = {sgn*s2, 0.0};
    else if (c == 2*l-a) base = {0.0, sgn*s2};
  }
  cplx ph = {1.0,0.0}, mi = {0.0,-1.0};
  for(int t=0;t<l;t++) ph = cmul(ph, mi);
  return cmul(base, ph);
}

__global__ void w3j_init(float* __restrict__ ws){
  __shared__ double red[128];
  __shared__ double snorm;
  const int spec[11][4] = {
    {0,0,0,T000},{0,1,1,T011},{1,0,1,T101},{1,1,0,T110},
    {0,2,2,T022},{2,0,2,T202},{2,2,0,T220},{1,2,1,T121},
    {2,1,1,T211},{1,1,2,T112},{2,2,2,T222}};
  int tbl = blockIdx.x;
  int l1 = spec[tbl][0], l2 = spec[tbl][1], l3 = spec[tbl][2], off = spec[tbl][3];
  int n1 = 2*l1+1, n2 = 2*l2+1, n3 = 2*l3+1, nel = n1*n2*n3;
  int t = threadIdx.x;
  double val = 0.0;
  if (t < nel){
    int k = t % n3, j = (t/n3) % n2, i = t/(n3*n2);
    for(int a=0;a<n1;a++){ int m1 = a-l1;
      for(int b=0;b<n2;b++){ int m2 = b-l2, m3 = m1+m2;
        if (m3 < -l3 || m3 > l3) continue;
        double C = dcgc(l1,m1,l2,m2,l3,m3);
        if (C == 0.0) continue;
        cplx q1 = qel(l1,a,i), q2 = qel(l2,b,j), q3 = qel(l3,l3+m3,k);
        q3.im = -q3.im;
        cplx p = cmul(cmul(q1,q2), q3);
        val += p.re * C;
      }
    }
  }
  red[t] = val*val;
  __syncthreads();
  for(int s=64; s>0; s>>=1){
    if (t < s) red[t] += red[t+s];
    __syncthreads();
  }
  if (t == 0) snorm = sqrt(red[0]);
  __syncthreads();
  if (t < nel) ws[off + t] = (float)(val / snorm);
}

// ============================================================================
// Weight prep: symmetrize (u<=v) + transpose-merge + fold coeffs (V1 layouts)
// ============================================================================
__device__ inline void pdec(int pid, int m, int& u, int& v){
  int uu = 0;
  while (pid >= m-uu){ pid -= (m-uu); uu++; }
  u = uu; v = uu + pid;
}

__global__ void prep3(const float* __restrict__ tp, const float* __restrict__ lin,
                      float* __restrict__ ws){
  const float PK0 = 1.0f/48.0f;
  const float PK1 = 1.0f/32.0f;
  const float PK2 = sqrtf(5.0f)/48.0f;
  int t = blockIdx.x*256 + threadIdx.x;
  if (t >= PREP_THREADS) return;
  if (t < 16896){                               // cw000p [pid528][w32]
    int w = t & 31, pid = t >> 5; int u,v; pdec(pid,32,u,v);
    float s = tp[TP000+(u*32+v)*32+w];
    if (u < v) s += tp[TP000+(v*32+u)*32+w];
    ws[OFF_CW000 + t] = PK0 * ws[T000] * s; return;
  }
  t -= 16896;
  if (t < 16896){                               // cw110p [pid528][w32]
    int w = t & 31, pid = t >> 5; int u,v; pdec(pid,32,u,v);
    float s = tp[TP110+(u*32+v)*32+w];
    if (u < v) s += tp[TP110+(v*32+u)*32+w];
    ws[OFF_CW110 + t] = PK0 * ws[T110] * s; return;
  }
  t -= 16896;
  if (t < 4352){                                // cw220p [pid136][w32]
    int w = t & 31, pid = t >> 5; int u,v; pdec(pid,16,u,v);
    float s = tp[TP220+(u*16+v)*32+w];
    if (u < v) s += tp[TP220+(v*16+u)*32+w];
    ws[OFF_CW220 + t] = PK0 * ws[T220] * s; return;
  }
  t -= 4352;
  if (t < 32768){                               // cw011 [q][p][w32]
    int w = t & 31, r = t >> 5; int p = r & 31, q = r >> 5;
    float d011 = ws[T011], d101 = ws[T101];
    float s = d011 * tp[TP011+(p*32+q)*32+w] + d101 * tp[TP101+(q*32+p)*32+w];
    ws[OFF_CW011 + t] = PK1 * s; return;
  }
  t -= 32768;
  if (t < 16384){                               // cw121 [b][q][w32]
    int w = t & 31, r = t >> 5; int q = r & 31, b = r >> 5;
    float s = tp[TP121+(q*16+b)*32+w] + tp[TP211+(b*32+q)*32+w];
    ws[OFF_CW121 + t] = PK1 * s; return;
  }
  t -= 16384;
  if (t < 8192){                                // cw022 [b][p][w16]
    int w = t & 15, r = t >> 4; int p = r & 31, b = r >> 5;
    float d022 = ws[T022], d202 = ws[T202];
    float s = d022 * tp[TP022+(p*16+b)*16+w] + d202 * tp[TP202+(b*32+p)*16+w];
    ws[OFF_CW022 + t] = PK2 * s; return;
  }
  t -= 8192;
  if (t < 8448){                                // cw112 [pid528][w16]
    int w = t & 15, pid = t >> 4; int u,v; pdec(pid,32,u,v);
    float s = tp[TP112+(u*32+v)*16+w];
    if (u < v) s += tp[TP112+(v*32+u)*16+w];
    ws[OFF_CW112 + t] = PK2 * s; return;
  }
  t -= 8448;
  if (t < 2176){                                // cw222 [pid136][w16]
    int w = t & 15, pid = t >> 4; int u,v; pdec(pid,16,u,v);
    float s = tp[TP222+(u*16+v)*16+w];
    if (u < v) s += tp[TP222+(v*16+u)*16+w];
    ws[OFF_CW222 + t] = PK2 * s; return;
  }
  t -= 2176;
  if (t < 1024){ ws[OFF_LIN0 + t] = 0.17677669529663687f * lin[t]; return; }
  t -= 1024;
  if (t < 1024){ ws[OFF_LIN1 + t] = 0.17677669529663687f * lin[1024+t]; return; }
  t -= 1024;
  ws[OFF_LIN2 + t] = 0.25f * lin[2048+t];
}

// ============================================================================
// Main kernel: 1 block = 64 nodes, x tile in LDS, 4 waves = output w-slices
// ============================================================================
#define XL(d) xL[(d)*65 + lane]

__global__ __launch_bounds__(256, 3)
void tp_block(const float* __restrict__ x, const float* __restrict__ ws,
              float* __restrict__ out, int N){
  __shared__ float xL[208*65];
  const int z0 = blockIdx.x * 64;
  const int tid = threadIdx.x;
  int nz = N - z0; if (nz > 64) nz = 64;
  // stage x[z0..z0+63][0..207] -> xL[d][zl]  (global coalesced, LDS stride-65)
  for (int i = tid; i < 64*208; i += 256){
    int zl = i / 208, d = i - zl*208;
    float v = (zl < nz) ? x[(size_t)z0*208 + i] : 0.f;
    xL[d*65 + zl] = v;
  }
  __syncthreads();
  const int wsl  = tid >> 6;   // w-slice 0..3
  const int lane = tid & 63;   // node within tile
  if (lane >= nz) return;
  float* __restrict__ oz = out + (size_t)(z0 + lane)*208;

  // =================== out irrep 0e : w-slice wsl*8..+7 ===================
  {
    float acc[8];
#pragma unroll
    for(int i=0;i<8;i++) acc[i]=0.f;
#define FMA8(P) { \
    acc[0]=fmaf(P,wA.x,acc[0]); acc[1]=fmaf(P,wA.y,acc[1]); \
    acc[2]=fmaf(P,wA.z,acc[2]); acc[3]=fmaf(P,wA.w,acc[3]); \
    acc[4]=fmaf(P,wB.x,acc[4]); acc[5]=fmaf(P,wB.y,acc[5]); \
    acc[6]=fmaf(P,wB.z,acc[6]); acc[7]=fmaf(P,wB.w,acc[7]); }
    const float* wp = ws + OFF_CW000 + wsl*8;
#pragma unroll 1
    for(int u=0;u<32;u++){
      float su = XL(u);
#pragma unroll 2
      for(int v=u;v<32;v++){
        float p = su * XL(v);
        float4 wA = *(const float4*)wp; float4 wB = *(const float4*)(wp+4);
        FMA8(p)
        wp += 32;
      }
    }
    const float* lw = ws + OFF_LIN0 + wsl*8;
#pragma unroll 1
    for(int u=0;u<32;u++){
      float su = XL(u);
      float4 wA = *(const float4*)lw; float4 wB = *(const float4*)(lw+4);
      FMA8(su)
      lw += 32;
    }
    wp = ws + OFF_CW110 + wsl*8;
#pragma unroll 1
    for(int u=0;u<32;u++){
      float a0=XL(32+3*u), a1=XL(33+3*u), a2=XL(34+3*u);
#pragma unroll 2
      for(int v=u;v<32;v++){
        float p = a0*XL(32+3*v) + a1*XL(33+3*v) + a2*XL(34+3*v);
        float4 wA = *(const float4*)wp; float4 wB = *(const float4*)(wp+4);
        FMA8(p)
        wp += 32;
      }
    }
    wp = ws + OFF_CW220 + wsl*8;
#pragma unroll 1
    for(int u=0;u<16;u++){
      float b0=XL(128+5*u),b1=XL(129+5*u),b2=XL(130+5*u),b3=XL(131+5*u),b4=XL(132+5*u);
#pragma unroll 2
      for(int v=u;v<16;v++){
        float p = b0*XL(128+5*v)+b1*XL(129+5*v)+b2*XL(130+5*v)+b3*XL(131+5*v)+b4*XL(132+5*v);
        float4 wA = *(const float4*)wp; float4 wB = *(const float4*)(wp+4);
        FMA8(p)
        wp += 32;
      }
    }
#undef FMA8
    float4 s0; s0.x=acc[0]; s0.y=acc[1]; s0.z=acc[2]; s0.w=acc[3];
    float4 s1; s1.x=acc[4]; s1.y=acc[5]; s1.z=acc[6]; s1.w=acc[7];
    *(float4*)(oz + wsl*8)     = s0;
    *(float4*)(oz + wsl*8 + 4) = s1;
  }

  // =================== out irrep 1o : w-slice wsl*8..+7 (x3 comps) =========
  {
    float acc[24];
#pragma unroll
    for(int i=0;i<24;i++) acc[i]=0.f;
#define FMA3(J,WT) { float wt_=(WT); \
    acc[3*(J)  ]=fmaf(p0,wt_,acc[3*(J)  ]); \
    acc[3*(J)+1]=fmaf(p1,wt_,acc[3*(J)+1]); \
    acc[3*(J)+2]=fmaf(p2,wt_,acc[3*(J)+2]); }
#define FMA24 { FMA3(0,wA.x) FMA3(1,wA.y) FMA3(2,wA.z) FMA3(3,wA.w) \
                FMA3(4,wB.x) FMA3(5,wB.y) FMA3(6,wB.z) FMA3(7,wB.w) }
    const float* wp = ws + OFF_CW011 + wsl*8;       // [q][p][w32]
#pragma unroll 1
    for(int q=0;q<32;q++){
      float vq0=XL(32+3*q), vq1=XL(33+3*q), vq2=XL(34+3*q);
#pragma unroll 2
      for(int p=0;p<32;p++){
        float sp = XL(p);
        float p0=sp*vq0, p1=sp*vq1, p2=sp*vq2;
        float4 wA = *(const float4*)wp; float4 wB = *(const float4*)(wp+4);
        FMA24
        wp += 32;
      }
    }
    wp = ws + OFF_CW121 + wsl*8;                    // [b][q][w32]
#pragma unroll 1
    for(int b=0;b<16;b++){
      float t0=XL(128+5*b), t1=XL(129+5*b), t2=XL(130+5*b), t3=XL(131+5*b), t4=XL(132+5*b);
      float q9[9];
#pragma unroll
      for(int a=0;a<3;a++)
#pragma unroll
        for(int c=0;c<3;c++){
          q9[a*3+c] = ws[T121+(a*5+0)*3+c]*t0 + ws[T121+(a*5+1)*3+c]*t1
                    + ws[T121+(a*5+2)*3+c]*t2 + ws[T121+(a*5+3)*3+c]*t3
                    + ws[T121+(a*5+4)*3+c]*t4;
        }
#pragma unroll 2
      for(int q=0;q<32;q++){
        float v0=XL(32+3*q), v1=XL(33+3*q), v2=XL(34+3*q);
        float p0 = v0*q9[0] + v1*q9[3] + v2*q9[6];
        float p1 = v0*q9[1] + v1*q9[4] + v2*q9[7];
        float p2 = v0*q9[2] + v1*q9[5] + v2*q9[8];
        float4 wA = *(const float4*)wp; float4 wB = *(const float4*)(wp+4);
        FMA24
        wp += 32;
      }
    }
    const float* lw = ws + OFF_LIN1 + wsl*8;
#pragma unroll 1
    for(int u=0;u<32;u++){
      float p0=XL(32+3*u), p1=XL(33+3*u), p2=XL(34+3*u);
      float4 wA = *(const float4*)lw; float4 wB = *(const float4*)(lw+4);
      FMA24
      lw += 32;
    }
#undef FMA24
#undef FMA3
    float* ob = oz + 32 + wsl*24;
#pragma unroll
    for(int j=0;j<6;j++){
      float4 s; s.x=acc[4*j]; s.y=acc[4*j+1]; s.z=acc[4*j+2]; s.w=acc[4*j+3];
      *(float4*)(ob + 4*j) = s;
    }
  }

  // =================== out irrep 2e : w-slice wsl*4..+3 (x5 comps) =========
  {
    float acc[20];
#pragma unroll
    for(int i=0;i<20;i++) acc[i]=0.f;
#define FMA5(J,WT) { float wt_=(WT); \
    acc[5*(J)  ]=fmaf(p0,wt_,acc[5*(J)  ]); \
    acc[5*(J)+1]=fmaf(p1,wt_,acc[5*(J)+1]); \
    acc[5*(J)+2]=fmaf(p2,wt_,acc[5*(J)+2]); \
    acc[5*(J)+3]=fmaf(p3,wt_,acc[5*(J)+3]); \
    acc[5*(J)+4]=fmaf(p4,wt_,acc[5*(J)+4]); }
#define FMA20 { FMA5(0,wA.x) FMA5(1,wA.y) FMA5(2,wA.z) FMA5(3,wA.w) }
    const float* wp = ws + OFF_CW022 + wsl*4;       // [b][p][w16]
#pragma unroll 1
    for(int b=0;b<16;b++){
      float t0=XL(128+5*b), t1=XL(129+5*b), t2=XL(130+5*b), t3=XL(131+5*b), t4=XL(132+5*b);
#pragma unroll 2
      for(int p=0;p<32;p++){
        float sp = XL(p);
        float p0=sp*t0, p1=sp*t1, p2=sp*t2, p3=sp*t3, p4=sp*t4;
        float4 wA = *(const float4*)wp;
        FMA20
        wp += 16;
      }
    }
    wp = ws + OFF_CW222 + wsl*4;                    // [pid136][w16]
#pragma unroll 1
    for(int u=0;u<16;u++){
      float tu0=XL(128+5*u), tu1=XL(129+5*u), tu2=XL(130+5*u), tu3=XL(131+5*u), tu4=XL(132+5*u);
      float r[25];
#pragma unroll
      for(int b=0;b<5;b++)
#pragma unroll
        for(int c=0;c<5;c++){
          r[b*5+c] = ws[T222+(0*5+b)*5+c]*tu0 + ws[T222+(1*5+b)*5+c]*tu1
                   + ws[T222+(2*5+b)*5+c]*tu2 + ws[T222+(3*5+b)*5+c]*tu3
                   + ws[T222+(4*5+b)*5+c]*tu4;
        }
#pragma unroll 2
      for(int v=u;v<16;v++){
        float s0=XL(128+5*v),s1=XL(129+5*v),s2=XL(130+5*v),s3=XL(131+5*v),s4=XL(132+5*v);
        float p0 = s0*r[0]+s1*r[5]+s2*r[10]+s3*r[15]+s4*r[20];
        float p1 = s0*r[1]+s1*r[6]+s2*r[11]+s3*r[16]+s4*r[21];
        float p2 = s0*r[2]+s1*r[7]+s2*r[12]+s3*r[17]+s4*r[22];
        float p3 = s0*r[3]+s1*r[8]+s2*r[13]+s3*r[18]+s4*r[23];
        float p4 = s0*r[4]+s1*r[9]+s2*r[14]+s3*r[19]+s4*r[24];
        float4 wA = *(const float4*)wp;
        FMA20
        wp += 16;
      }
    }
    const float* lw = ws + OFF_LIN2 + wsl*4;
#pragma unroll 1
    for(int u=0;u<16;u++){
      float p0=XL(128+5*u), p1=XL(129+5*u), p2=XL(130+5*u), p3=XL(131+5*u), p4=XL(132+5*u);
      float4 wA = *(const float4*)lw;
      FMA20
      lw += 16;
    }
    wp = ws + OFF_CW112 + wsl*4;                    // [pid528][w16]
#pragma unroll 1
    for(int u=0;u<32;u++){
      float u0=XL(32+3*u), u1=XL(33+3*u), u2=XL(34+3*u);
      float r[15];
#pragma unroll
      for(int b=0;b<3;b++)
#pragma unroll
        for(int c=0;c<5;c++)
          r[b*5+c] = ws[T112+(0*3+b)*5+c]*u0 + ws[T112+(1*3+b)*5+c]*u1
                   + ws[T112+(2*3+b)*5+c]*u2;
#pragma unroll 2
      for(int v=u;v<32;v++){
        float v0=XL(32+3*v), v1=XL(33+3*v), v2=XL(34+3*v);
        float p0 = v0*r[0]+v1*r[5]+v2*r[10];
        float p1 = v0*r[1]+v1*r[6]+v2*r[11];
        float p2 = v0*r[2]+v1*r[7]+v2*r[12];
        float p3 = v0*r[3]+v1*r[8]+v2*r[13];
        float p4 = v0*r[4]+v1*r[9]+v2*r[14];
        float4 wA = *(const float4*)wp;
        FMA20
        wp += 16;
      }
    }
#undef FMA20
#undef FMA5
    float* ob = oz + 128 + wsl*20;
#pragma unroll
    for(int j=0;j<5;j++){
      float4 s; s.x=acc[4*j]; s.y=acc[4*j+1]; s.z=acc[4*j+2]; s.w=acc[4*j+3];
      *(float4*)(ob + 4*j) = s;
    }
  }
}
#undef XL

// ============================================================================
extern "C" void kernel_launch(void* const* d_in, const int* in_sizes, int n_in,
                              void* d_out, int out_size, void* d_ws, size_t ws_size,
                              hipStream_t stream) {
  const float* x   = (const float*)d_in[0];
  const float* tpw = (const float*)d_in[1];
  const float* lnw = (const float*)d_in[2];
  float* out = (float*)d_out;
  float* ws  = (float*)d_ws;
  const int N = in_sizes[0]/208;

  w3j_init<<<11, 128, 0, stream>>>(ws);
  prep3<<<(PREP_THREADS+255)/256, 256, 0, stream>>>(tpw, lnw, ws);
  tp_block<<<(N+63)/64, 256, 0, stream>>>(x, ws, out, N);
}

// Round 4
// 2761.809 us; speedup vs baseline: 1.5525x; 1.5525x over previous
//
#include <hip/hip_runtime.h>

// ============================================================================
// V4: LDS-resident x tile (V3's win: FETCH 4.25GB -> 0.27GB) + full-width
// inner bodies (V1's win) via output-region wave split:
//   wave0: 0e all 32w + 2e w[11..15]   (~89k FMA)
//   wave1: 1o w[0..15]                 (~84k)
//   wave2: 1o w[16..31]                (~84k)
//   wave3: 2e w[0..10]                 (~85k)
// Bodies 32-55 FMA per weight row; weights wave-uniform; x from LDS/regs.
// ============================================================================
#define T000 0
#define T011 1
#define T101 10
#define T110 19
#define T022 28
#define T202 53
#define T220 78
#define T121 103
#define T211 148
#define T112 193
#define T222 238
#define NTAB 363

#define TP000 0
#define TP011 32768
#define TP022 65536
#define TP101 73728
#define TP110 106496
#define TP112 139264
#define TP121 155648
#define TP202 172032
#define TP211 180224
#define TP220 196608
#define TP222 204800

#define OFF_CW000 512      // [pid528][w32]
#define OFF_CW110 17408    // [pid528][w32]
#define OFF_CW220 34304    // [pid136][w32]
#define OFF_CW011 38656    // [q32][p32][w32]  merged 011+101
#define OFF_CW121 71424    // [b16][q32][w32]  merged 121+211
#define OFF_CW022 87808    // [b16][p32][w16]  merged 022+202
#define OFF_CW112 96000    // [pid528][w16]
#define OFF_CW222 104448   // [pid136][w16]
#define OFF_LIN0  106624   // [32][32]
#define OFF_LIN1  107648   // [32][32]
#define OFF_LIN2  108672   // [16][16]
#define PREP_THREADS 108416

// ============================================================================
// Parallel device-side Wigner 3j (verified in V1-V3)
// ============================================================================
struct cplx { double re, im; };
__device__ inline cplx cmul(cplx a, cplx b){ return {a.re*b.re - a.im*b.im, a.re*b.im + a.im*b.re}; }

__device__ double dfact(int n){ double r=1; for(int i=2;i<=n;i++) r*=i; return r; }

__device__ double dcgc(int j1,int m1,int j2,int m2,int j3,int m3){
  if (m3 != m1+m2) return 0.0;
  double pref = sqrt((2.0*j3+1)*dfact(j3+j1-j2)*dfact(j3-j1+j2)*dfact(j1+j2-j3)/dfact(j1+j2+j3+1));
  pref *= sqrt(dfact(j3+m3)*dfact(j3-m3)*dfact(j1-m1)*dfact(j1+m1)*dfact(j2-m2)*dfact(j2+m2));
  int k0 = max(0, max(j2-j3-m1, j1-j3+m2));
  int k1 = min(j1+j2-j3, min(j1-m1, j2+m2));
  double s = 0.0;
  for(int k=k0;k<=k1;k++){
    double d = dfact(k)*dfact(j1+j2-j3-k)*dfact(j1-m1-k)*dfact(j2+m2-k)*dfact(j3-j2+m1+k)*dfact(j3-j1-m2+k);
    s += ((k&1)?-1.0:1.0)/d;
  }
  return pref*s;
}

__device__ cplx qel(int l, int a, int c){
  const double s2 = 0.7071067811865475244;
  cplx base = {0.0, 0.0};
  if (a < l){
    if (c == 2*l-a) base = {s2, 0.0};
    else if (c == a) base = {0.0, -s2};
  } else if (a == l){
    if (c == l) base = {1.0, 0.0};
  } else {
    double sgn = ((a-l)&1)? -1.0 : 1.0;
    if (c == a) base = {sgn*s2, 0.0};
    else if (c == 2*l-a) base = {0.0, sgn*s2};
  }
  cplx ph = {1.0,0.0}, mi = {0.0,-1.0};
  for(int t=0;t<l;t++) ph = cmul(ph, mi);
  return cmul(base, ph);
}

__global__ void w3j_init(float* __restrict__ ws){
  __shared__ double red[128];
  __shared__ double snorm;
  const int spec[11][4] = {
    {0,0,0,T000},{0,1,1,T011},{1,0,1,T101},{1,1,0,T110},
    {0,2,2,T022},{2,0,2,T202},{2,2,0,T220},{1,2,1,T121},
    {2,1,1,T211},{1,1,2,T112},{2,2,2,T222}};
  int tbl = blockIdx.x;
  int l1 = spec[tbl][0], l2 = spec[tbl][1], l3 = spec[tbl][2], off = spec[tbl][3];
  int n1 = 2*l1+1, n2 = 2*l2+1, n3 = 2*l3+1, nel = n1*n2*n3;
  int t = threadIdx.x;
  double val = 0.0;
  if (t < nel){
    int k = t % n3, j = (t/n3) % n2, i = t/(n3*n2);
    for(int a=0;a<n1;a++){ int m1 = a-l1;
      for(int b=0;b<n2;b++){ int m2 = b-l2, m3 = m1+m2;
        if (m3 < -l3 || m3 > l3) continue;
        double C = dcgc(l1,m1,l2,m2,l3,m3);
        if (C == 0.0) continue;
        cplx q1 = qel(l1,a,i), q2 = qel(l2,b,j), q3 = qel(l3,l3+m3,k);
        q3.im = -q3.im;
        cplx p = cmul(cmul(q1,q2), q3);
        val += p.re * C;
      }
    }
  }
  red[t] = val*val;
  __syncthreads();
  for(int s=64; s>0; s>>=1){
    if (t < s) red[t] += red[t+s];
    __syncthreads();
  }
  if (t == 0) snorm = sqrt(red[0]);
  __syncthreads();
  if (t < nel) ws[off + t] = (float)(val / snorm);
}

// ============================================================================
// Weight prep (V1/V3 layouts, verified)
// ============================================================================
__device__ inline void pdec(int pid, int m, int& u, int& v){
  int uu = 0;
  while (pid >= m-uu){ pid -= (m-uu); uu++; }
  u = uu; v = uu + pid;
}

__global__ void prep3(const float* __restrict__ tp, const float* __restrict__ lin,
                      float* __restrict__ ws){
  const float PK0 = 1.0f/48.0f;
  const float PK1 = 1.0f/32.0f;
  const float PK2 = sqrtf(5.0f)/48.0f;
  int t = blockIdx.x*256 + threadIdx.x;
  if (t >= PREP_THREADS) return;
  if (t < 16896){                               // cw000p [pid528][w32]
    int w = t & 31, pid = t >> 5; int u,v; pdec(pid,32,u,v);
    float s = tp[TP000+(u*32+v)*32+w];
    if (u < v) s += tp[TP000+(v*32+u)*32+w];
    ws[OFF_CW000 + t] = PK0 * ws[T000] * s; return;
  }
  t -= 16896;
  if (t < 16896){                               // cw110p [pid528][w32]
    int w = t & 31, pid = t >> 5; int u,v; pdec(pid,32,u,v);
    float s = tp[TP110+(u*32+v)*32+w];
    if (u < v) s += tp[TP110+(v*32+u)*32+w];
    ws[OFF_CW110 + t] = PK0 * ws[T110] * s; return;
  }
  t -= 16896;
  if (t < 4352){                                // cw220p [pid136][w32]
    int w = t & 31, pid = t >> 5; int u,v; pdec(pid,16,u,v);
    float s = tp[TP220+(u*16+v)*32+w];
    if (u < v) s += tp[TP220+(v*16+u)*32+w];
    ws[OFF_CW220 + t] = PK0 * ws[T220] * s; return;
  }
  t -= 4352;
  if (t < 32768){                               // cw011 [q][p][w32]
    int w = t & 31, r = t >> 5; int p = r & 31, q = r >> 5;
    float d011 = ws[T011], d101 = ws[T101];
    float s = d011 * tp[TP011+(p*32+q)*32+w] + d101 * tp[TP101+(q*32+p)*32+w];
    ws[OFF_CW011 + t] = PK1 * s; return;
  }
  t -= 32768;
  if (t < 16384){                               // cw121 [b][q][w32]
    int w = t & 31, r = t >> 5; int q = r & 31, b = r >> 5;
    float s = tp[TP121+(q*16+b)*32+w] + tp[TP211+(b*32+q)*32+w];
    ws[OFF_CW121 + t] = PK1 * s; return;
  }
  t -= 16384;
  if (t < 8192){                                // cw022 [b][p][w16]
    int w = t & 15, r = t >> 4; int p = r & 31, b = r >> 5;
    float d022 = ws[T022], d202 = ws[T202];
    float s = d022 * tp[TP022+(p*16+b)*16+w] + d202 * tp[TP202+(b*32+p)*16+w];
    ws[OFF_CW022 + t] = PK2 * s; return;
  }
  t -= 8192;
  if (t < 8448){                                // cw112 [pid528][w16]
    int w = t & 15, pid = t >> 4; int u,v; pdec(pid,32,u,v);
    float s = tp[TP112+(u*32+v)*16+w];
    if (u < v) s += tp[TP112+(v*32+u)*16+w];
    ws[OFF_CW112 + t] = PK2 * s; return;
  }
  t -= 8448;
  if (t < 2176){                                // cw222 [pid136][w16]
    int w = t & 15, pid = t >> 4; int u,v; pdec(pid,16,u,v);
    float s = tp[TP222+(u*16+v)*16+w];
    if (u < v) s += tp[TP222+(v*16+u)*16+w];
    ws[OFF_CW222 + t] = PK2 * s; return;
  }
  t -= 2176;
  if (t < 1024){ ws[OFF_LIN0 + t] = 0.17677669529663687f * lin[t]; return; }
  t -= 1024;
  if (t < 1024){ ws[OFF_LIN1 + t] = 0.17677669529663687f * lin[1024+t]; return; }
  t -= 1024;
  ws[OFF_LIN2 + t] = 0.25f * lin[2048+t];
}

// ============================================================================
// Per-wave workers. XL(d): per-lane x value from LDS (stride-65, conflict-free)
// ============================================================================
#define XL(d) xb[(d)*65]

__device__ inline void ld32(float* wt, const float* row){
#pragma unroll
  for(int j=0;j<8;j++) *(float4*)(wt+4*j) = *(const float4*)(row+4*j);
}
__device__ inline void ld16(float* wt, const float* row){
#pragma unroll
  for(int j=0;j<4;j++) *(float4*)(wt+4*j) = *(const float4*)(row+4*j);
}

// ---- out irrep 0e, all 32 w ----
__device__ void do0e(const float* xb, const float* __restrict__ ws, float* oz){
  float acc[32];
#pragma unroll
  for(int i=0;i<32;i++) acc[i]=0.f;
  const float* wp = ws + OFF_CW000;
#pragma unroll 1
  for(int u=0;u<32;u++){
    float su = XL(u);
#pragma unroll 2
    for(int v=u;v<32;v++){
      float p = su * XL(v);
      float wt[32]; ld32(wt, wp);
#pragma unroll
      for(int w=0;w<32;w++) acc[w] = fmaf(p, wt[w], acc[w]);
      wp += 32;
    }
  }
  const float* lw = ws + OFF_LIN0;
#pragma unroll 1
  for(int u=0;u<32;u++){
    float su = XL(u);
    float wt[32]; ld32(wt, lw);
#pragma unroll
    for(int w=0;w<32;w++) acc[w] = fmaf(su, wt[w], acc[w]);
    lw += 32;
  }
  wp = ws + OFF_CW110;
#pragma unroll 1
  for(int u=0;u<32;u++){
    float a0=XL(32+3*u), a1=XL(33+3*u), a2=XL(34+3*u);
#pragma unroll 2
    for(int v=u;v<32;v++){
      float p = a0*XL(32+3*v) + a1*XL(33+3*v) + a2*XL(34+3*v);
      float wt[32]; ld32(wt, wp);
#pragma unroll
      for(int w=0;w<32;w++) acc[w] = fmaf(p, wt[w], acc[w]);
      wp += 32;
    }
  }
  wp = ws + OFF_CW220;
#pragma unroll 1
  for(int u=0;u<16;u++){
    float b0=XL(128+5*u),b1=XL(129+5*u),b2=XL(130+5*u),b3=XL(131+5*u),b4=XL(132+5*u);
#pragma unroll 2
    for(int v=u;v<16;v++){
      float p = b0*XL(128+5*v)+b1*XL(129+5*v)+b2*XL(130+5*v)+b3*XL(131+5*v)+b4*XL(132+5*v);
      float wt[32]; ld32(wt, wp);
#pragma unroll
      for(int w=0;w<32;w++) acc[w] = fmaf(p, wt[w], acc[w]);
      wp += 32;
    }
  }
#pragma unroll
  for(int j=0;j<8;j++){
    float4 s; s.x=acc[4*j]; s.y=acc[4*j+1]; s.z=acc[4*j+2]; s.w=acc[4*j+3];
    *(float4*)(oz + 4*j) = s;
  }
}

// ---- out irrep 1o, w-half at W0 (16 w x 3 comps) ----
template<int W0>
__device__ void do1o(const float* xb, const float* __restrict__ ws, float* oz){
  float acc[48];
#pragma unroll
  for(int i=0;i<48;i++) acc[i]=0.f;
  const float* wp = ws + OFF_CW011 + W0;      // [q][p][w32] slice
  const float* lw = ws + OFF_LIN1 + W0;
#pragma unroll 1
  for(int q=0;q<32;q++){
    float vq0=XL(32+3*q), vq1=XL(33+3*q), vq2=XL(34+3*q);
#pragma unroll 2
    for(int p=0;p<32;p++){
      float sp = XL(p);
      float p0=sp*vq0, p1=sp*vq1, p2=sp*vq2;
      float wt[16]; ld16(wt, wp);
#pragma unroll
      for(int w=0;w<16;w++){
        acc[3*w  ] = fmaf(p0, wt[w], acc[3*w  ]);
        acc[3*w+1] = fmaf(p1, wt[w], acc[3*w+1]);
        acc[3*w+2] = fmaf(p2, wt[w], acc[3*w+2]);
      }
      wp += 32;
    }
    { // lin1 row q folded in (u == q)
      float wt[16]; ld16(wt, lw);
#pragma unroll
      for(int w=0;w<16;w++){
        acc[3*w  ] = fmaf(vq0, wt[w], acc[3*w  ]);
        acc[3*w+1] = fmaf(vq1, wt[w], acc[3*w+1]);
        acc[3*w+2] = fmaf(vq2, wt[w], acc[3*w+2]);
      }
      lw += 32;
    }
  }
  wp = ws + OFF_CW121 + W0;                   // [b][q][w32] slice
#pragma unroll 1
  for(int b=0;b<16;b++){
    float t0=XL(128+5*b), t1=XL(129+5*b), t2=XL(130+5*b), t3=XL(131+5*b), t4=XL(132+5*b);
    float q9[9];
#pragma unroll
    for(int a=0;a<3;a++)
#pragma unroll
      for(int c=0;c<3;c++){
        q9[a*3+c] = ws[T121+(a*5+0)*3+c]*t0 + ws[T121+(a*5+1)*3+c]*t1
                  + ws[T121+(a*5+2)*3+c]*t2 + ws[T121+(a*5+3)*3+c]*t3
                  + ws[T121+(a*5+4)*3+c]*t4;
      }
#pragma unroll 2
    for(int q=0;q<32;q++){
      float v0=XL(32+3*q), v1=XL(33+3*q), v2=XL(34+3*q);
      float p0 = v0*q9[0] + v1*q9[3] + v2*q9[6];
      float p1 = v0*q9[1] + v1*q9[4] + v2*q9[7];
      float p2 = v0*q9[2] + v1*q9[5] + v2*q9[8];
      float wt[16]; ld16(wt, wp);
#pragma unroll
      for(int w=0;w<16;w++){
        acc[3*w  ] = fmaf(p0, wt[w], acc[3*w  ]);
        acc[3*w+1] = fmaf(p1, wt[w], acc[3*w+1]);
        acc[3*w+2] = fmaf(p2, wt[w], acc[3*w+2]);
      }
      wp += 32;
    }
  }
  float* ob = oz + 32 + 3*W0;
#pragma unroll
  for(int j=0;j<12;j++){
    float4 s; s.x=acc[4*j]; s.y=acc[4*j+1]; s.z=acc[4*j+2]; s.w=acc[4*j+3];
    *(float4*)(ob + 4*j) = s;
  }
}

// ---- out irrep 2e, w-slice [WOFF, WOFF+NW) x 5 comps ----
template<int WOFF,int NW>
__device__ inline void ld2e(float* wt, const float* row){
  if constexpr (WOFF == 0){            // NW == 11
    *(float4*)(wt  ) = *(const float4*)(row  );
    *(float4*)(wt+4) = *(const float4*)(row+4);
    wt[8] = row[8]; wt[9] = row[9]; wt[10] = row[10];
  } else {                             // WOFF == 11, NW == 5
    wt[0] = row[11];
    *(float4*)(wt+1) = *(const float4*)(row+12);
  }
}

template<int WOFF,int NW>
__device__ void do2e(const float* xb, const float* __restrict__ ws, float* oz){
  float acc[5*NW];
#pragma unroll
  for(int i=0;i<5*NW;i++) acc[i]=0.f;
  const float* wp = ws + OFF_CW022;           // [b][p][w16]
#pragma unroll 1
  for(int b=0;b<16;b++){
    float t0=XL(128+5*b), t1=XL(129+5*b), t2=XL(130+5*b), t3=XL(131+5*b), t4=XL(132+5*b);
#pragma unroll 2
    for(int p=0;p<32;p++){
      float sp = XL(p);
      float p0=sp*t0, p1=sp*t1, p2=sp*t2, p3=sp*t3, p4=sp*t4;
      float wt[NW]; ld2e<WOFF,NW>(wt, wp);
#pragma unroll
      for(int w=0;w<NW;w++){
        acc[5*w  ] = fmaf(p0, wt[w], acc[5*w  ]);
        acc[5*w+1] = fmaf(p1, wt[w], acc[5*w+1]);
        acc[5*w+2] = fmaf(p2, wt[w], acc[5*w+2]);
        acc[5*w+3] = fmaf(p3, wt[w], acc[5*w+3]);
        acc[5*w+4] = fmaf(p4, wt[w], acc[5*w+4]);
      }
      wp += 16;
    }
  }
  wp = ws + OFF_CW222;                        // [pid136][w16]
#pragma unroll 1
  for(int u=0;u<16;u++){
    float tu0=XL(128+5*u), tu1=XL(129+5*u), tu2=XL(130+5*u), tu3=XL(131+5*u), tu4=XL(132+5*u);
    float r[25];
#pragma unroll
    for(int b=0;b<5;b++)
#pragma unroll
      for(int c=0;c<5;c++){
        r[b*5+c] = ws[T222+(0*5+b)*5+c]*tu0 + ws[T222+(1*5+b)*5+c]*tu1
                 + ws[T222+(2*5+b)*5+c]*tu2 + ws[T222+(3*5+b)*5+c]*tu3
                 + ws[T222+(4*5+b)*5+c]*tu4;
      }
#pragma unroll 2
    for(int v=u;v<16;v++){
      float s0=XL(128+5*v),s1=XL(129+5*v),s2=XL(130+5*v),s3=XL(131+5*v),s4=XL(132+5*v);
      float p0 = s0*r[0]+s1*r[5]+s2*r[10]+s3*r[15]+s4*r[20];
      float p1 = s0*r[1]+s1*r[6]+s2*r[11]+s3*r[16]+s4*r[21];
      float p2 = s0*r[2]+s1*r[7]+s2*r[12]+s3*r[17]+s4*r[22];
      float p3 = s0*r[3]+s1*r[8]+s2*r[13]+s3*r[18]+s4*r[23];
      float p4 = s0*r[4]+s1*r[9]+s2*r[14]+s3*r[19]+s4*r[24];
      float wt[NW]; ld2e<WOFF,NW>(wt, wp);
#pragma unroll
      for(int w=0;w<NW;w++){
        acc[5*w  ] = fmaf(p0, wt[w], acc[5*w  ]);
        acc[5*w+1] = fmaf(p1, wt[w], acc[5*w+1]);
        acc[5*w+2] = fmaf(p2, wt[w], acc[5*w+2]);
        acc[5*w+3] = fmaf(p3, wt[w], acc[5*w+3]);
        acc[5*w+4] = fmaf(p4, wt[w], acc[5*w+4]);
      }
      wp += 16;
    }
  }
  const float* lw = ws + OFF_LIN2;            // [16][16]
#pragma unroll 1
  for(int u=0;u<16;u++){
    float p0=XL(128+5*u), p1=XL(129+5*u), p2=XL(130+5*u), p3=XL(131+5*u), p4=XL(132+5*u);
    float wt[NW]; ld2e<WOFF,NW>(wt, lw);
#pragma unroll
    for(int w=0;w<NW;w++){
      acc[5*w  ] = fmaf(p0, wt[w], acc[5*w  ]);
      acc[5*w+1] = fmaf(p1, wt[w], acc[5*w+1]);
      acc[5*w+2] = fmaf(p2, wt[w], acc[5*w+2]);
      acc[5*w+3] = fmaf(p3, wt[w], acc[5*w+3]);
      acc[5*w+4] = fmaf(p4, wt[w], acc[5*w+4]);
    }
    lw += 16;
  }
  wp = ws + OFF_CW112;                        // [pid528][w16]
#pragma unroll 1
  for(int u=0;u<32;u++){
    float u0=XL(32+3*u), u1=XL(33+3*u), u2=XL(34+3*u);
    float r[15];
#pragma unroll
    for(int b=0;b<3;b++)
#pragma unroll
      for(int c=0;c<5;c++)
        r[b*5+c] = ws[T112+(0*3+b)*5+c]*u0 + ws[T112+(1*3+b)*5+c]*u1
                 + ws[T112+(2*3+b)*5+c]*u2;
#pragma unroll 2
    for(int v=u;v<32;v++){
      float v0=XL(32+3*v), v1=XL(33+3*v), v2=XL(34+3*v);
      float p0 = v0*r[0]+v1*r[5]+v2*r[10];
      float p1 = v0*r[1]+v1*r[6]+v2*r[11];
      float p2 = v0*r[2]+v1*r[7]+v2*r[12];
      float p3 = v0*r[3]+v1*r[8]+v2*r[13];
      float p4 = v0*r[4]+v1*r[9]+v2*r[14];
      float wt[NW]; ld2e<WOFF,NW>(wt, wp);
#pragma unroll
      for(int w=0;w<NW;w++){
        acc[5*w  ] = fmaf(p0, wt[w], acc[5*w  ]);
        acc[5*w+1] = fmaf(p1, wt[w], acc[5*w+1]);
        acc[5*w+2] = fmaf(p2, wt[w], acc[5*w+2]);
        acc[5*w+3] = fmaf(p3, wt[w], acc[5*w+3]);
        acc[5*w+4] = fmaf(p4, wt[w], acc[5*w+4]);
      }
      wp += 16;
    }
  }
  // store: 2e slice at oz[128 + 5*WOFF ...]
  float* ob = oz + 128 + 5*WOFF;
  if constexpr (NW == 11){
    // oz+128 is 16B-aligned: 13 float4 + 3 scalars
#pragma unroll
    for(int j=0;j<13;j++){
      float4 s; s.x=acc[4*j]; s.y=acc[4*j+1]; s.z=acc[4*j+2]; s.w=acc[4*j+3];
      *(float4*)(ob + 4*j) = s;
    }
    ob[52]=acc[52]; ob[53]=acc[53]; ob[54]=acc[54];
  } else {
    // oz+183: 1 scalar then oz+184 16B-aligned: 6 float4
    ob[0] = acc[0];
#pragma unroll
    for(int j=0;j<6;j++){
      float4 s; s.x=acc[1+4*j]; s.y=acc[2+4*j]; s.z=acc[3+4*j]; s.w=acc[4+4*j];
      *(float4*)(ob + 1 + 4*j) = s;
    }
  }
}

// ============================================================================
// Main kernel: 1 block = 64 nodes; x tile in LDS; waves = output regions
// ============================================================================
__global__ __launch_bounds__(256, 3)
void tp_block(const float* __restrict__ x, const float* __restrict__ ws,
              float* __restrict__ out, int N){
  __shared__ float xL[208*65];
  const int z0 = blockIdx.x * 64;
  const int tid = threadIdx.x;
  int nz = N - z0; if (nz > 64) nz = 64;
  // stage: global float4 reads (coalesced), LDS transpose writes
  for (int i = tid; i < 64*52; i += 256){
    int zl = i / 52, c4 = i - zl*52;
    int d = c4*4;
    float4 v;
    if (zl < nz) v = *(const float4*)(x + (size_t)(z0+zl)*208 + d);
    else { v.x=0.f; v.y=0.f; v.z=0.f; v.w=0.f; }
    xL[(d  )*65 + zl] = v.x;
    xL[(d+1)*65 + zl] = v.y;
    xL[(d+2)*65 + zl] = v.z;
    xL[(d+3)*65 + zl] = v.w;
  }
  __syncthreads();
  const int wsl  = tid >> 6;
  const int lane = tid & 63;
  if (lane >= nz) return;
  float* oz = out + (size_t)(z0 + lane)*208;
  const float* xb = xL + lane;

  if (wsl == 0){
    do0e(xb, ws, oz);
    do2e<11,5>(xb, ws, oz);
  } else if (wsl == 1){
    do1o<0>(xb, ws, oz);
  } else if (wsl == 2){
    do1o<16>(xb, ws, oz);
  } else {
    do2e<0,11>(xb, ws, oz);
  }
}
#undef XL

// ============================================================================
extern "C" void kernel_launch(void* const* d_in, const int* in_sizes, int n_in,
                              void* d_out, int out_size, void* d_ws, size_t ws_size,
                              hipStream_t stream) {
  const float* x   = (const float*)d_in[0];
  const float* tpw = (const float*)d_in[1];
  const float* lnw = (const float*)d_in[2];
  float* out = (float*)d_out;
  float* ws  = (float*)d_ws;
  const int N = in_sizes[0]/208;

  w3j_init<<<11, 128, 0, stream>>>(ws);
  prep3<<<(PREP_THREADS+255)/256, 256, 0, stream>>>(tpw, lnw, ws);
  tp_block<<<(N+63)/64, 256, 0, stream>>>(x, ws, out, N);
}